// Round 5
// baseline (349.091 us; speedup 1.0000x reference)
//
#include <hip/hip_runtime.h>
#include <hip/hip_bf16.h>

typedef __bf16 bf16;
typedef __attribute__((ext_vector_type(8))) __bf16 bf16x8;
typedef __attribute__((ext_vector_type(4))) __bf16 bf16x4;
typedef __attribute__((ext_vector_type(16))) float f32x16;

#define N_ROWS 16384
#define DIM 256
#define NT 128
#define LSTRIP 8
#define NSTRIPS 1088 /* sum_{it} ceil((128-it)/8) */
#define SQK1 4.53981608f /* sqrt(1/(0.07*ln2)): pre-scale so exp(z) = 2^dot' */
#define LN2F 0.69314718056f

#define WS_T_OFF (N_ROWS * DIM * 2)
#define WS_D_OFF (WS_T_OFF + N_ROWS * 4)

#define GLOAD_LDS(g, l)                                        \
    __builtin_amdgcn_global_load_lds(                          \
        (const __attribute__((address_space(1))) void*)(g),    \
        (__attribute__((address_space(3))) void*)(l), 16, 0, 0)

// Kernel 1: L2-normalize rows, scale by SQK1, emit bf16 A' to ws. Zeros T[]
// and d_out. Dg[row] = s2' = sum(bf16(SQK1*a)^2) — exactly the MFMA diagonal,
// so its bf16 rounding error cancels: loss_i = ln2*(log2(T'_i) - s2'_i).
__global__ void __launch_bounds__(256) normalize_kernel(const float* __restrict__ in,
                                                        bf16* __restrict__ out,
                                                        float* __restrict__ Tg,
                                                        float* __restrict__ Dg,
                                                        float* __restrict__ loss_out) {
    if (blockIdx.x == 0 && threadIdx.x == 0) loss_out[0] = 0.0f;
    if (blockIdx.x < 64) Tg[blockIdx.x * 256 + threadIdx.x] = 0.0f;

    const int row  = blockIdx.x * 4 + (threadIdx.x >> 6);
    const int lane = threadIdx.x & 63;
    const float4* rp = (const float4*)(in + (size_t)row * DIM);
    float4 v = rp[lane];
    float ss = v.x * v.x + v.y * v.y + v.z * v.z + v.w * v.w;
#pragma unroll
    for (int m = 1; m < 64; m <<= 1) ss += __shfl_xor(ss, m, 64);
    float inv = SQK1 / fmaxf(sqrtf(ss), 1e-12f);
    bf16x4 o;
    o[0] = (bf16)(v.x * inv);
    o[1] = (bf16)(v.y * inv);
    o[2] = (bf16)(v.z * inv);
    o[3] = (bf16)(v.w * inv);
    *(bf16x4*)(out + (size_t)row * DIM + lane * 4) = o;

    float f0 = (float)o[0], f1 = (float)o[1], f2 = (float)o[2], f3 = (float)o[3];
    float s2 = f0 * f0 + f1 * f1 + f2 * f2 + f3 * f3;
#pragma unroll
    for (int m = 1; m < 64; m <<= 1) s2 += __shfl_xor(s2, m, 64);
    if (lane == 0) Dg[row] = s2;
}

// Tree-reduce 16 floats across the 32 `lo` lanes; every lane ends with the
// full sum for register index r = (lo>>1)&15. (Verified R4: absmax 0.)
#define TREE16(R, out)                                                     \
    do {                                                                   \
        float w8[8], w4[4], w2[2], w1, g_;                                 \
        _Pragma("unroll") for (int i_ = 0; i_ < 8; ++i_) {                 \
            g_ = (lo & 16) ? R[i_] : R[i_ + 8];                            \
            w8[i_] = ((lo & 16) ? R[i_ + 8] : R[i_]) + __shfl_xor(g_, 16); \
        }                                                                  \
        _Pragma("unroll") for (int i_ = 0; i_ < 4; ++i_) {                 \
            g_ = (lo & 8) ? w8[i_] : w8[i_ + 4];                           \
            w4[i_] = ((lo & 8) ? w8[i_ + 4] : w8[i_]) + __shfl_xor(g_, 8); \
        }                                                                  \
        _Pragma("unroll") for (int i_ = 0; i_ < 2; ++i_) {                 \
            g_ = (lo & 4) ? w4[i_] : w4[i_ + 2];                           \
            w2[i_] = ((lo & 4) ? w4[i_ + 2] : w4[i_]) + __shfl_xor(g_, 4); \
        }                                                                  \
        g_ = (lo & 2) ? w2[0] : w2[1];                                     \
        w1 = ((lo & 2) ? w2[1] : w2[0]) + __shfl_xor(g_, 2);               \
        out = w1 + __shfl_xor(w1, 1);                                      \
    } while (0)

// Kernel 2: symmetric A'A'^T + softmax denominator. Grid = 1088 strips:
// strip = (it, up to 8 j-tiles). A-frags for the block's 128 rows live in
// registers (64 rows/wave = 128 VGPRs, loaded once per strip). B staged per
// k-half (128 cols x 128 k = 32 KB) double-buffered via global_load_lds with
// XOR chunk-swizzle on the GLOBAL side -> conflict-free b128 reads.
// Pipeline: raw s_barrier + manual s_waitcnt vmcnt(8) (prefetch stays in
// flight across the barrier — no full drain).
__global__ void __launch_bounds__(256, 2)
loss_kernel(const bf16* __restrict__ A, float* __restrict__ Tg) {
    __shared__ bf16 Bs[2][16384]; // 2 x 32 KB

    const int tid = threadIdx.x;
    const int w  = tid >> 6;
    const int l  = tid & 63;
    const int lo = l & 31, hi = l >> 5;

    // strip decode
    int it = 0, rem = blockIdx.x;
    for (;;) {
        int nch = (NT - it + LSTRIP - 1) / LSTRIP;
        if (rem < nch) break;
        rem -= nch;
        ++it;
    }
    const int jt0 = it + rem * LSTRIP;
    const int jt1 = (jt0 + LSTRIP < NT) ? (jt0 + LSTRIP) : NT;
    const int H = 2 * (jt1 - jt0);

    // persistent A fragments: rows arow..arow+63 (A layout: row=lo, k=hi*8+j)
    const int arow = (w >> 1) * 64;
    bf16x8 af[2][16];
    {
        const bf16* ap = A + (size_t)(it * 128 + arow + lo) * DIM + hi * 8;
#pragma unroll
        for (int t = 0; t < 2; ++t)
#pragma unroll
            for (int k = 0; k < 16; ++k)
                af[t][k] = *(const bf16x8*)(ap + t * 32 * DIM + k * 16);
    }

    // DMA lane constants: instr q covers rows 32w+4q..+3; lane: row_local =
    // l>>4, slot s = l&15 holds global chunk (s&8)|((s&7)^(row&7)).
    const int sidx = l & 15;
    const int rloc = l >> 4;
    const int c_e = (sidx & 8) | ((sidx & 7) ^ rloc);
    const int c_o = (sidx & 8) | ((sidx & 7) ^ (rloc ^ 4));
    const int dma_lane_base = (32 * w + rloc) * DIM;

    // fragment-read constants: row rb2 slots at rb2*128 elems; global chunk
    // cc lives at slot (cc&8)|((cc&7)^(rb2&7))
    const int mx = lo & 7;
    const int cb0 = ((w & 1) * 64 + lo) * 128;
    const int cb1 = cb0 + 32 * 128;

    float s0[16], s1[16];
#pragma unroll
    for (int r = 0; r < 16; ++r) { s0[r] = 0.f; s1[r] = 0.f; }

    f32x16 c00, c01, c10, c11;

#define ISSUE(hh)                                                            \
    do {                                                                     \
        const bf16* tb_ = A + (size_t)(jt0 + ((hh) >> 1)) * 128 * DIM +      \
                          ((hh) & 1) * 128;                                  \
        bf16* lb_ = &Bs[(hh) & 1][w * 4096];                                 \
        _Pragma("unroll") for (int q_ = 0; q_ < 8; ++q_) {                   \
            const int c_ = (q_ & 1) ? c_o : c_e;                             \
            GLOAD_LDS(tb_ + dma_lane_base + q_ * 4 * DIM + c_ * 8,           \
                      lb_ + q_ * 512);                                       \
        }                                                                    \
    } while (0)

    ISSUE(0);
    for (int h = 0; h < H; ++h) {
        asm volatile("s_barrier" ::: "memory"); // (a) all waves done reading buf[(h+1)&1]
        if (h + 1 < H) {
            ISSUE(h + 1);
            asm volatile("s_waitcnt vmcnt(8)" ::: "memory"); // batch h done, h+1 in flight
        } else {
            asm volatile("s_waitcnt vmcnt(0)" ::: "memory");
        }
        asm volatile("s_barrier" ::: "memory"); // (b) half h visible to all waves

        const bf16* bs = &Bs[h & 1][0];
        const int khb = (h & 1) * 8;
        if (!(h & 1)) {
#pragma unroll
            for (int r = 0; r < 16; ++r) { c00[r] = 0.f; c01[r] = 0.f; c10[r] = 0.f; c11[r] = 0.f; }
        }
#pragma unroll
        for (int k16 = 0; k16 < 8; ++k16) {
            const int cc = k16 * 2 + hi;
            const int slot = (cc & 8) | ((cc & 7) ^ mx);
            bf16x8 b0 = *(const bf16x8*)&bs[cb0 + slot * 8];
            bf16x8 b1 = *(const bf16x8*)&bs[cb1 + slot * 8];
            c00 = __builtin_amdgcn_mfma_f32_32x32x16_bf16(af[0][khb + k16], b0, c00, 0, 0, 0);
            c10 = __builtin_amdgcn_mfma_f32_32x32x16_bf16(af[1][khb + k16], b0, c10, 0, 0, 0);
            c01 = __builtin_amdgcn_mfma_f32_32x32x16_bf16(af[0][khb + k16], b1, c01, 0, 0, 0);
            c11 = __builtin_amdgcn_mfma_f32_32x32x16_bf16(af[1][khb + k16], b1, c11, 0, 0, 0);
        }
        if (h & 1) {
            // tile epilogue: e = 2^dot' (no fma — A pre-scaled); diag is max
            const int tile = jt0 + (h >> 1);
            float cs0 = 0.f, cs1 = 0.f;
#pragma unroll
            for (int r = 0; r < 16; ++r) {
                float e00 = __builtin_amdgcn_exp2f(c00[r]);
                float e01 = __builtin_amdgcn_exp2f(c01[r]);
                float e10 = __builtin_amdgcn_exp2f(c10[r]);
                float e11 = __builtin_amdgcn_exp2f(c11[r]);
                s0[r] += e00 + e01;
                s1[r] += e10 + e11;
                cs0 += e00 + e10;
                cs1 += e01 + e11;
            }
            cs0 += __shfl_xor(cs0, 32);
            cs1 += __shfl_xor(cs1, 32);
            if (tile != it && hi == 0) {
                atomicAdd(&Tg[tile * 128 + (w & 1) * 64 + lo], cs0);
                atomicAdd(&Tg[tile * 128 + (w & 1) * 64 + 32 + lo], cs1);
            }
        }
    }

    // strip end: row sums. C/D row = (r&3)+8*(r>>2)+4*hi.
    float t0, t1;
    TREE16(s0, t0);
    TREE16(s1, t1);
    const int r = (lo >> 1) & 15;
    const int rowoff = (r & 3) + 8 * (r >> 2) + 4 * hi;
    atomicAdd(&Tg[it * 128 + arow + ((l & 1) ? 32 : 0) + rowoff], (l & 1) ? t1 : t0);
#undef ISSUE
}

// Kernel 3: loss_i = ln2*(log2(T'_i) - s2'_i), mean over rows.
__global__ void __launch_bounds__(256) final_kernel(const float* __restrict__ Tg,
                                                    const float* __restrict__ Dg,
                                                    float* __restrict__ out) {
    __shared__ float red[4];
    const int i = blockIdx.x * 256 + threadIdx.x;
    float c = LN2F * (__log2f(Tg[i]) - Dg[i]) * (1.0f / (float)N_ROWS);
#pragma unroll
    for (int m = 1; m < 64; m <<= 1) c += __shfl_xor(c, m, 64);
    if ((threadIdx.x & 63) == 0) red[threadIdx.x >> 6] = c;
    __syncthreads();
    if (threadIdx.x == 0)
        atomicAdd(out, red[0] + red[1] + red[2] + red[3]);
}

extern "C" void kernel_launch(void* const* d_in, const int* in_sizes, int n_in,
                              void* d_out, int out_size, void* d_ws, size_t ws_size,
                              hipStream_t stream) {
    const float* emb = (const float*)d_in[0];
    float* out = (float*)d_out;
    bf16* Abf = (bf16*)d_ws;
    float* Tg = (float*)((char*)d_ws + WS_T_OFF);
    float* Dg = (float*)((char*)d_ws + WS_D_OFF);

    hipLaunchKernelGGL(normalize_kernel, dim3(N_ROWS / 4), dim3(256), 0, stream,
                       emb, Abf, Tg, Dg, out);
    hipLaunchKernelGGL(loss_kernel, dim3(NSTRIPS), dim3(256), 0, stream,
                       Abf, Tg);
    hipLaunchKernelGGL(final_kernel, dim3(N_ROWS / 256), dim3(256), 0, stream,
                       Tg, Dg, out);
}

// Round 6
// 258.481 us; speedup vs baseline: 1.3505x; 1.3505x over previous
//
#include <hip/hip_runtime.h>
#include <hip/hip_bf16.h>

typedef __bf16 bf16;
typedef __attribute__((ext_vector_type(8))) __bf16 bf16x8;
typedef __attribute__((ext_vector_type(4))) __bf16 bf16x4;
typedef __attribute__((ext_vector_type(16))) float f32x16;

#define N_ROWS 16384
#define DIM 256
#define NT 128
#define LSTRIP 8
#define NSTRIPS 1088     /* sum_{it} ceil((128-it)/8) */
#define SQK1 4.53981608f /* sqrt(1/(0.07*ln2)): A pre-scaled so e^{z} = 2^{dot'} */
#define LN2F 0.69314718056f

#define WS_T_OFF (N_ROWS * DIM * 2)
#define WS_D_OFF (WS_T_OFF + N_ROWS * 4)

// Kernel 1: L2-normalize rows, scale by SQK1, emit bf16 A' to ws. Zeros T[]
// and d_out. Dg[row] = s2' = sum(bf16(SQK1*a)^2) = the MFMA diagonal, so the
// diagonal's bf16 rounding error cancels: loss_i = ln2*(log2(T'_i) - s2'_i).
__global__ void __launch_bounds__(256) normalize_kernel(const float* __restrict__ in,
                                                        bf16* __restrict__ out,
                                                        float* __restrict__ Tg,
                                                        float* __restrict__ Dg,
                                                        float* __restrict__ loss_out) {
    if (blockIdx.x == 0 && threadIdx.x == 0) loss_out[0] = 0.0f;
    if (blockIdx.x < 64) Tg[blockIdx.x * 256 + threadIdx.x] = 0.0f;

    const int row  = blockIdx.x * 4 + (threadIdx.x >> 6);
    const int lane = threadIdx.x & 63;
    const float4* rp = (const float4*)(in + (size_t)row * DIM);
    float4 v = rp[lane];
    float ss = v.x * v.x + v.y * v.y + v.z * v.z + v.w * v.w;
#pragma unroll
    for (int m = 1; m < 64; m <<= 1) ss += __shfl_xor(ss, m, 64);
    float inv = SQK1 / fmaxf(sqrtf(ss), 1e-12f);
    bf16x4 o;
    o[0] = (bf16)(v.x * inv);
    o[1] = (bf16)(v.y * inv);
    o[2] = (bf16)(v.z * inv);
    o[3] = (bf16)(v.w * inv);
    *(bf16x4*)(out + (size_t)row * DIM + lane * 4) = o;

    float f0 = (float)o[0], f1 = (float)o[1], f2 = (float)o[2], f3 = (float)o[3];
    float s2 = f0 * f0 + f1 * f1 + f2 * f2 + f3 * f3;
#pragma unroll
    for (int m = 1; m < 64; m <<= 1) s2 += __shfl_xor(s2, m, 64);
    if (lane == 0) Dg[row] = s2;
}

// Tree-reduce 16 floats across the 32 `lo` lanes; every lane ends with the
// full sum for register index r = (lo>>1)&15. (Correctness-proven R4/R5.)
#define TREE16(R, out)                                                     \
    do {                                                                   \
        float w8[8], w4[4], w2[2], w1, g_;                                 \
        _Pragma("unroll") for (int i_ = 0; i_ < 8; ++i_) {                 \
            g_ = (lo & 16) ? R[i_] : R[i_ + 8];                            \
            w8[i_] = ((lo & 16) ? R[i_ + 8] : R[i_]) + __shfl_xor(g_, 16); \
        }                                                                  \
        _Pragma("unroll") for (int i_ = 0; i_ < 4; ++i_) {                 \
            g_ = (lo & 8) ? w8[i_] : w8[i_ + 4];                           \
            w4[i_] = ((lo & 8) ? w8[i_ + 4] : w8[i_]) + __shfl_xor(g_, 8); \
        }                                                                  \
        _Pragma("unroll") for (int i_ = 0; i_ < 2; ++i_) {                 \
            g_ = (lo & 4) ? w4[i_] : w4[i_ + 2];                           \
            w2[i_] = ((lo & 4) ? w4[i_ + 2] : w4[i_]) + __shfl_xor(g_, 4); \
        }                                                                  \
        g_ = (lo & 2) ? w2[0] : w2[1];                                     \
        w1 = ((lo & 2) ? w2[1] : w2[0]) + __shfl_xor(g_, 2);               \
        out = w1 + __shfl_xor(w1, 1);                                      \
    } while (0)

// Kernel 2: symmetric A'A'^T + softmax denominator. NO LDS in the GEMM.
// Strip = (it, up to 8 j-tiles). Wave layout in a 128x128 tile:
// rows (w>>1)*64, cols (w&1)*64, as 2x2 of 32x32x16 MFMA. A fragments for
// the wave's 64 rows live in registers (af[2][16], STATIC indexing only —
// R5's dynamic index caused scratch demotion). B fragments are loaded
// directly from global (L1/L2; wave pairs share addresses -> L1 hits),
// register double-buffered one k16-step ahead. Row sums: per-tile TREE16,
// accumulated in 2 scalars across the strip, atomics at strip end.
__global__ void __launch_bounds__(256, 2)
loss_kernel(const bf16* __restrict__ A, float* __restrict__ Tg) {
    const int tid = threadIdx.x;
    const int w  = tid >> 6;
    const int l  = tid & 63;
    const int lo = l & 31, hi = l >> 5;

    // strip decode
    int it = 0, rem = blockIdx.x;
    for (;;) {
        int nch = (NT - it + LSTRIP - 1) / LSTRIP;
        if (rem < nch) break;
        rem -= nch;
        ++it;
    }
    const int jt0 = it + rem * LSTRIP;
    const int jt1 = (jt0 + LSTRIP < NT) ? (jt0 + LSTRIP) : NT;

    const int arow = (w >> 1) * 64;

    // persistent A fragments (A-operand layout: m = lo, k = hi*8 + j)
    bf16x8 af0[16], af1[16];
    {
        const bf16* ap0 = A + (size_t)(it * 128 + arow + lo) * DIM + hi * 8;
        const bf16* ap1 = ap0 + 32 * DIM;
#pragma unroll
        for (int k = 0; k < 16; ++k) {
            af0[k] = *(const bf16x8*)(ap0 + k * 16);
            af1[k] = *(const bf16x8*)(ap1 + k * 16);
        }
    }

    // B pointers for this wave's 64 cols (B-operand: n = lo, k = hi*8 + j)
    const bf16* bp0 = A + (size_t)(jt0 * 128 + (w & 1) * 64 + lo) * DIM + hi * 8;
    const bf16* bp1 = bp0 + 32 * DIM;

    bf16x8 p0 = *(const bf16x8*)bp0;  // k16=0 preload
    bf16x8 p1 = *(const bf16x8*)bp1;
    bf16x8 q0, q1;

    float st0 = 0.f, st1 = 0.f;  // strip row-sum accumulators (post-tree)

    for (int jt = jt0; jt < jt1; ++jt) {
        f32x16 c00, c01, c10, c11;
#pragma unroll
        for (int r = 0; r < 16; ++r) { c00[r] = 0.f; c01[r] = 0.f; c10[r] = 0.f; c11[r] = 0.f; }

#pragma unroll
        for (int k = 0; k < 16; ++k) {
            bf16x8 cb0, cb1;
            if ((k & 1) == 0) { cb0 = p0; cb1 = p1; } else { cb0 = q0; cb1 = q1; }
            if (k < 15) {
                if ((k & 1) == 0) {
                    q0 = *(const bf16x8*)(bp0 + (k + 1) * 16);
                    q1 = *(const bf16x8*)(bp1 + (k + 1) * 16);
                } else {
                    p0 = *(const bf16x8*)(bp0 + (k + 1) * 16);
                    p1 = *(const bf16x8*)(bp1 + (k + 1) * 16);
                }
            } else {
                bp0 += 128 * DIM;  // next tile's cols
                bp1 += 128 * DIM;
                if (jt + 1 < jt1) {
                    p0 = *(const bf16x8*)bp0;
                    p1 = *(const bf16x8*)bp1;
                }
            }
            c00 = __builtin_amdgcn_mfma_f32_32x32x16_bf16(af0[k], cb0, c00, 0, 0, 0);
            c10 = __builtin_amdgcn_mfma_f32_32x32x16_bf16(af1[k], cb0, c10, 0, 0, 0);
            c01 = __builtin_amdgcn_mfma_f32_32x32x16_bf16(af0[k], cb1, c01, 0, 0, 0);
            c11 = __builtin_amdgcn_mfma_f32_32x32x16_bf16(af1[k], cb1, c11, 0, 0, 0);
        }

        // epilogue: e = 2^{dot'} (A pre-scaled; diagonal is the provable max)
        float R0[16], R1[16];
        float cs0 = 0.f, cs1 = 0.f;
#pragma unroll
        for (int r = 0; r < 16; ++r) {
            float e00 = __builtin_amdgcn_exp2f(c00[r]);
            float e01 = __builtin_amdgcn_exp2f(c01[r]);
            float e10 = __builtin_amdgcn_exp2f(c10[r]);
            float e11 = __builtin_amdgcn_exp2f(c11[r]);
            R0[r] = e00 + e01;
            R1[r] = e10 + e11;
            cs0 += e00 + e10;
            cs1 += e01 + e11;
        }
        // col sums -> Tg[jt rows] (symmetry); skip on diagonal tile
        cs0 += __shfl_xor(cs0, 32);
        cs1 += __shfl_xor(cs1, 32);
        if (jt != it && hi == 0) {
            atomicAdd(&Tg[jt * 128 + (w & 1) * 64 + lo], cs0);
            atomicAdd(&Tg[jt * 128 + (w & 1) * 64 + 32 + lo], cs1);
        }
        // row sums: tree-reduce this tile, accumulate scalar across strip
        float t0, t1;
        TREE16(R0, t0);
        TREE16(R1, t1);
        st0 += t0;
        st1 += t1;
    }

    // strip end: one row atomic per lane. C/D row = (r&3)+8*(r>>2)+4*hi.
    const int r = (lo >> 1) & 15;
    const int rowoff = (r & 3) + 8 * (r >> 2) + 4 * hi;
    atomicAdd(&Tg[it * 128 + arow + ((l & 1) ? 32 : 0) + rowoff], (l & 1) ? st1 : st0);
}

// Kernel 3: loss_i = ln2*(log2(T'_i) - s2'_i), mean over rows.
__global__ void __launch_bounds__(256) final_kernel(const float* __restrict__ Tg,
                                                    const float* __restrict__ Dg,
                                                    float* __restrict__ out) {
    __shared__ float red[4];
    const int i = blockIdx.x * 256 + threadIdx.x;
    float c = LN2F * (__log2f(Tg[i]) - Dg[i]) * (1.0f / (float)N_ROWS);
#pragma unroll
    for (int m = 1; m < 64; m <<= 1) c += __shfl_xor(c, m, 64);
    if ((threadIdx.x & 63) == 0) red[threadIdx.x >> 6] = c;
    __syncthreads();
    if (threadIdx.x == 0)
        atomicAdd(out, red[0] + red[1] + red[2] + red[3]);
}

extern "C" void kernel_launch(void* const* d_in, const int* in_sizes, int n_in,
                              void* d_out, int out_size, void* d_ws, size_t ws_size,
                              hipStream_t stream) {
    const float* emb = (const float*)d_in[0];
    float* out = (float*)d_out;
    bf16* Abf = (bf16*)d_ws;
    float* Tg = (float*)((char*)d_ws + WS_T_OFF);
    float* Dg = (float*)((char*)d_ws + WS_D_OFF);

    hipLaunchKernelGGL(normalize_kernel, dim3(N_ROWS / 4), dim3(256), 0, stream,
                       emb, Abf, Tg, Dg, out);
    hipLaunchKernelGGL(loss_kernel, dim3(NSTRIPS), dim3(256), 0, stream,
                       Abf, Tg);
    hipLaunchKernelGGL(final_kernel, dim3(N_ROWS / 256), dim3(256), 0, stream,
                       Tg, Dg, out);
}